// Round 5
// baseline (288.656 us; speedup 1.0000x reference)
//
#include <hip/hip_runtime.h>
#include <cstdint>
#include <cstddef>

#define B_   16
#define N_   2048
#define DN   64
#define DQ   256     // 4*D_NET
#define HID_ 128
#define SEQ_ 18
#define OUTR 2066
#define KVB  32

typedef __attribute__((ext_vector_type(4)))  float f32x4;
typedef __attribute__((ext_vector_type(16))) float f32x16;
typedef __attribute__((ext_vector_type(8)))  short bf16x8;

__device__ __forceinline__ unsigned cvtpk(float lo, float hi) {
  unsigned w;
  asm("v_cvt_pk_bf16_f32 %0, %1, %2" : "=v"(w) : "v"(lo), "v"(hi));
  return w;
}
__device__ __forceinline__ bf16x8 cvt8(const float* p) {
  f32x4 a = *(const f32x4*)p, b = *(const f32x4*)(p + 4);
  union { unsigned u[4]; bf16x8 v; } r;
  r.u[0] = cvtpk(a[0], a[1]); r.u[1] = cvtpk(a[2], a[3]);
  r.u[2] = cvtpk(b[0], b[1]); r.u[3] = cvtpk(b[2], b[3]);
  return r.v;
}
__device__ __forceinline__ float hadd4(f32x4 v) { return (v[0] + v[1]) + (v[2] + v[3]); }

// redistribute 32x32 C-layout rows into B-fragment k-order
__device__ __forceinline__ bf16x8 mkfrag(unsigned wa, unsigned wb,
                                         unsigned wc, unsigned wd, bool hi) {
  unsigned sa = (unsigned)__shfl_xor((int)wa, 32);
  unsigned sb = (unsigned)__shfl_xor((int)wb, 32);
  unsigned sc = (unsigned)__shfl_xor((int)wc, 32);
  unsigned sd = (unsigned)__shfl_xor((int)wd, 32);
  union { unsigned u[4]; bf16x8 v; } r;
  r.u[0] = hi ? sc : wa;
  r.u[1] = hi ? sd : wb;
  r.u[2] = hi ? wc : sa;
  r.u[3] = hi ? wd : sb;
  return r.v;
}

// ======================= proj + sfc (merged, concurrent) =======================
struct SfcS {
  float xs[SEQ_][132];
  float qkv[SEQ_][388];
  float scs[4][SEQ_][19];
  float sinb[SEQ_][32];
  float ffh[SEQ_][8];
  float maskv[SEQ_];
};
union PSmem { short wl[24576]; SfcS sfc; };

__device__ void proj_body(int gid, short* wl,
    const float* __restrict__ net, const float* __restrict__ Wq, const float* __restrict__ bq,
    const float* __restrict__ Wk, const float* __restrict__ bk,
    const float* __restrict__ Wv, const float* __restrict__ bv,
    short* __restrict__ Qb, short* __restrict__ Kb, short* __restrict__ Vt) {
  const int b = gid >> 4;
  const int r0 = (gid & 15) * 128;
  const int t = threadIdx.x;
  const int w = t >> 6, lane = t & 63, ln = lane & 15, g = lane >> 4;
  const int xk = (ln & 7) << 4;

  const float* Ws[3] = {Wq, Wk, Wv};
#pragma unroll
  for (int m = 0; m < 3; ++m)
#pragma unroll
    for (int it = 0; it < 16; ++it) {
      int idx = it * 256 + t;
      int row = idx >> 4, c8 = idx & 15;
      f32x4 v = *(const f32x4*)(Ws[m] + row * 64 + c8 * 4);
      int byo = m * 16384 + row * 128 + ((c8 * 8) ^ ((row & 7) << 4));
      *(uint2*)((char*)wl + byo) = make_uint2(cvtpk(v[0], v[1]), cvtpk(v[2], v[3]));
    }

  bf16x8 af[2][2];
#pragma unroll
  for (int rg = 0; rg < 2; ++rg)
#pragma unroll
    for (int c = 0; c < 2; ++c)
      af[rg][c] = cvt8(net + ((size_t)b * N_ + r0 + rg * 64 + w * 16 + ln) * DN + c * 32 + g * 8);
  __syncthreads();

#pragma unroll
  for (int m = 0; m < 2; ++m) {
    const float* bias = (m == 0) ? bq : bk;
    short* dst = (m == 0) ? Qb : Kb;
    const float sc = (m == 0) ? 0.125f : 1.0f;     // fold 1/sqrt(64) into Q
#pragma unroll
    for (int rg = 0; rg < 2; ++rg) {
      const int rw = r0 + rg * 64 + w * 16;
#pragma unroll
      for (int tt = 0; tt < 16; ++tt) {
        f32x4 acc = {0.f, 0.f, 0.f, 0.f};
#pragma unroll
        for (int c = 0; c < 2; ++c) {
          int byo = m * 16384 + (tt * 16 + ln) * 128 + ((c * 64 + g * 16) ^ xk);
          bf16x8 wf = *(const bf16x8*)((char*)wl + byo);
          acc = __builtin_amdgcn_mfma_f32_16x16x32_bf16(wf, af[rg][c], acc, 0, 0, 0);
        }
        f32x4 b4 = *(const f32x4*)(bias + tt * 16 + g * 4);
        uint2 u = make_uint2(cvtpk((acc[0] + b4[0]) * sc, (acc[1] + b4[1]) * sc),
                             cvtpk((acc[2] + b4[2]) * sc, (acc[3] + b4[3]) * sc));
        *(uint2*)(dst + ((size_t)b * N_ + rw + ln) * DQ + tt * 16 + g * 4) = u;
      }
    }
  }
#pragma unroll
  for (int rg = 0; rg < 2; ++rg) {
    const int rw = r0 + rg * 64 + w * 16;
#pragma unroll
    for (int tt = 0; tt < 16; ++tt) {
      f32x4 acc = {0.f, 0.f, 0.f, 0.f};
#pragma unroll
      for (int c = 0; c < 2; ++c) {
        int byo = 32768 + (tt * 16 + ln) * 128 + ((c * 64 + g * 16) ^ xk);
        bf16x8 wf = *(const bf16x8*)((char*)wl + byo);
        acc = __builtin_amdgcn_mfma_f32_16x16x32_bf16(af[rg][c], wf, acc, 0, 0, 0);
      }
      float bias = bv[tt * 16 + ln];
      uint2 u = make_uint2(cvtpk(acc[0] + bias, acc[1] + bias),
                           cvtpk(acc[2] + bias, acc[3] + bias));
      *(uint2*)(Vt + ((size_t)b * DQ + tt * 16 + ln) * N_ + rw + g * 4) = u;
    }
  }
}

__device__ __forceinline__ void par_ln(SfcS& S, const float* __restrict__ lw,
                                       const float* __restrict__ lb, int w, int lane) {
  float w0 = lw[lane * 2], w1 = lw[lane * 2 + 1];
  float b0 = lb[lane * 2], b1 = lb[lane * 2 + 1];
  for (int r = w; r < SEQ_; r += 4) {
    float2 v = *(const float2*)&S.qkv[r][128 + lane * 2];
    float s1 = v.x + v.y;
    float s2 = v.x * v.x + v.y * v.y;
#pragma unroll
    for (int off = 1; off < 64; off <<= 1) {
      s1 += __shfl_xor(s1, off);
      s2 += __shfl_xor(s2, off);
    }
    float mu = s1 * 0.0078125f;
    float var = s2 * 0.0078125f - mu * mu;
    float rsd = rsqrtf(var + 1e-5f);
    S.xs[r][lane * 2]     = (v.x - mu) * rsd * w0 + b0;
    S.xs[r][lane * 2 + 1] = (v.y - mu) * rsd * w1 + b1;
  }
}

__device__ void sfc_body(
    int b, SfcS& S,
    const float* __restrict__ sfc_state, const int* __restrict__ node_pair,
    const float* __restrict__ node_embed, const float* __restrict__ sfcW,
    const float* __restrict__ sfcb, const float* __restrict__ pos,
    const float* __restrict__ qkvW, const float* __restrict__ qkvB,
    const float* __restrict__ outW, const float* __restrict__ outB,
    const float* __restrict__ ln1w, const float* __restrict__ ln1b,
    const float* __restrict__ l1w, const float* __restrict__ l1b,
    const float* __restrict__ l2w, const float* __restrict__ l2b,
    const float* __restrict__ ln2w, const float* __restrict__ ln2b,
    float* __restrict__ out) {
  const int t = threadIdx.x;
  const int w = t >> 6, lane = t & 63;

  for (int i = t; i < SEQ_ * 32; i += 256) {
    int s = i >> 5, d = i & 31;
    float v;
    if (s == 0)       v = node_embed[node_pair[b * 2 + 0] * 32 + d];
    else if (s == 17) v = node_embed[node_pair[b * 2 + 1] * 32 + d];
    else              v = sfc_state[((size_t)b * 16 + (s - 1)) * 32 + d];
    S.sinb[s][d] = v;
  }
  __syncthreads();
  if (t < SEQ_) {
    float sum = 0.f;
#pragma unroll
    for (int d = 0; d < 32; ++d) sum += fabsf(S.sinb[t][d]);
    S.maskv[t] = (sum == 0.f) ? -1e9f : 0.f;
  }
  {
    int hh = t & 127, half = t >> 7;
    f32x4 wr[8];
#pragma unroll
    for (int j = 0; j < 8; ++j) wr[j] = *(const f32x4*)(sfcW + hh * 32 + j * 4);
    for (int si = half * 9; si < half * 9 + 9; ++si) {
      f32x4 a = {0.f, 0.f, 0.f, 0.f};
#pragma unroll
      for (int j = 0; j < 8; ++j) a += wr[j] * (*(const f32x4*)&S.sinb[si][j * 4]);
      S.xs[si][hh] = hadd4(a) + sfcb[hh] + pos[si * HID_ + hh];
    }
  }
  __syncthreads();

  for (int ll = 0; ll < 2; ++ll) {
    for (int oo = t; oo < 384; oo += 256) {
      const float* wp = qkvW + ((size_t)ll * 384 + oo) * HID_;
      float acc[SEQ_];
#pragma unroll
      for (int s = 0; s < SEQ_; ++s) acc[s] = 0.f;
      for (int kb = 0; kb < 4; ++kb) {
        f32x4 wv[8];
#pragma unroll
        for (int j = 0; j < 8; ++j) wv[j] = *(const f32x4*)(wp + kb * 32 + j * 4);
#pragma unroll
        for (int s = 0; s < SEQ_; ++s) {
          f32x4 a = {0.f, 0.f, 0.f, 0.f};
#pragma unroll
          for (int j = 0; j < 8; ++j) a += wv[j] * (*(const f32x4*)&S.xs[s][kb * 32 + j * 4]);
          acc[s] += hadd4(a);
        }
      }
      float bias = qkvB[ll * 384 + oo];
#pragma unroll
      for (int s = 0; s < SEQ_; ++s) S.qkv[s][oo] = acc[s] + bias;
    }
    __syncthreads();
    for (int i = t; i < 4 * SEQ_ * SEQ_; i += 256) {
      int hh = i / (SEQ_ * SEQ_), rem = i - hh * SEQ_ * SEQ_;
      int qi = rem / SEQ_, kj = rem - qi * SEQ_;
      f32x4 a = {0.f, 0.f, 0.f, 0.f};
#pragma unroll
      for (int j = 0; j < 8; ++j)
        a += (*(const f32x4*)&S.qkv[qi][hh * 32 + j * 4]) *
             (*(const f32x4*)&S.qkv[kj][128 + hh * 32 + j * 4]);
      S.scs[hh][qi][kj] = hadd4(a) * 0.17677669529663687f + S.maskv[kj];
    }
    __syncthreads();
    if (t < 4 * SEQ_) {
      int hh = t / SEQ_, qi = t - hh * SEQ_;
      float mx = -1e30f;
#pragma unroll
      for (int j = 0; j < SEQ_; ++j) mx = fmaxf(mx, S.scs[hh][qi][j]);
      float sum = 0.f;
#pragma unroll
      for (int j = 0; j < SEQ_; ++j) {
        float e = __expf(S.scs[hh][qi][j] - mx);
        S.scs[hh][qi][j] = e; sum += e;
      }
      float inv = 1.f / sum;
#pragma unroll
      for (int j = 0; j < SEQ_; ++j) S.scs[hh][qi][j] *= inv;
    }
    __syncthreads();
    for (int i = t; i < SEQ_ * HID_; i += 256) {
      int s = i >> 7, hd = i & 127, hh = hd >> 5;
      float a = 0.f;
#pragma unroll
      for (int j = 0; j < SEQ_; ++j) a += S.scs[hh][s][j] * S.qkv[j][256 + hd];
      S.qkv[s][hd] = a;
    }
    __syncthreads();
    {
      int hh = t & 127, half = t >> 7;
      const float* wp = outW + ((size_t)ll * HID_ + hh) * HID_;
      float acc2[9];
#pragma unroll
      for (int si = 0; si < 9; ++si) acc2[si] = 0.f;
      for (int kb = 0; kb < 4; ++kb) {
        f32x4 wv[8];
#pragma unroll
        for (int j = 0; j < 8; ++j) wv[j] = *(const f32x4*)(wp + kb * 32 + j * 4);
#pragma unroll
        for (int si = 0; si < 9; ++si) {
          int s = half * 9 + si;
          f32x4 a = {0.f, 0.f, 0.f, 0.f};
#pragma unroll
          for (int j = 0; j < 8; ++j) a += wv[j] * (*(const f32x4*)&S.qkv[s][kb * 32 + j * 4]);
          acc2[si] += hadd4(a);
        }
      }
      float bias = outB[ll * HID_ + hh];
#pragma unroll
      for (int si = 0; si < 9; ++si) {
        int s = half * 9 + si;
        S.qkv[s][128 + hh] = S.xs[s][hh] + acc2[si] + bias;
      }
    }
    __syncthreads();
    par_ln(S, ln1w + ll * HID_, ln1b + ll * HID_, w, lane);
    __syncthreads();
    if (t < SEQ_ * 8) {
      int s = t >> 3, oo = t & 7;
      const float* wp = l1w + ((size_t)ll * 8 + oo) * HID_;
      f32x4 a = {0.f, 0.f, 0.f, 0.f};
#pragma unroll
      for (int j = 0; j < 32; ++j)
        a += (*(const f32x4*)(wp + j * 4)) * (*(const f32x4*)&S.xs[s][j * 4]);
      S.ffh[s][oo] = fmaxf(hadd4(a) + l1b[ll * 8 + oo], 0.f);
    }
    __syncthreads();
    for (int i = t; i < SEQ_ * HID_; i += 256) {
      int s = i >> 7, h2 = i & 127;
      const float* wp = l2w + ((size_t)ll * HID_ + h2) * 8;
      float a = 0.f;
#pragma unroll
      for (int j = 0; j < 8; ++j) a += wp[j] * S.ffh[s][j];
      S.qkv[s][128 + h2] = S.xs[s][h2] + a + l2b[ll * HID_ + h2];
    }
    __syncthreads();
    par_ln(S, ln2w + ll * HID_, ln2b + ll * HID_, w, lane);
    __syncthreads();
  }
  for (int i = t; i < SEQ_ * HID_; i += 256) {
    int s = i >> 7, h2 = i & 127;
    out[((size_t)b * OUTR + 2048 + s) * HID_ + h2] = S.xs[s][h2];
  }
}

__global__ __launch_bounds__(256) void proj_sfc_kernel(
    const float* __restrict__ net, const float* __restrict__ Wq, const float* __restrict__ bq,
    const float* __restrict__ Wk, const float* __restrict__ bk,
    const float* __restrict__ Wv, const float* __restrict__ bv,
    short* __restrict__ Qb, short* __restrict__ Kb, short* __restrict__ Vt,
    const float* __restrict__ sfc_state, const int* __restrict__ node_pair,
    const float* __restrict__ node_embed, const float* __restrict__ sfcW,
    const float* __restrict__ sfcb, const float* __restrict__ pos,
    const float* __restrict__ qkvW, const float* __restrict__ qkvB,
    const float* __restrict__ outW, const float* __restrict__ outB,
    const float* __restrict__ ln1w, const float* __restrict__ ln1b,
    const float* __restrict__ l1w, const float* __restrict__ l1b,
    const float* __restrict__ l2w, const float* __restrict__ l2b,
    const float* __restrict__ ln2w, const float* __restrict__ ln2b,
    float* __restrict__ out) {
  __shared__ PSmem sm;
  if (blockIdx.x < 256) {
    proj_body(blockIdx.x, sm.wl, net, Wq, bq, Wk, bk, Wv, bv, Qb, Kb, Vt);
  } else {
    sfc_body(blockIdx.x - 256, sm.sfc, sfc_state, node_pair, node_embed, sfcW, sfcb, pos,
             qkvW, qkvB, outW, outB, ln1w, ln1b, l1w, l1b, l2w, l2b, ln2w, ln2b, out);
  }
}

// ======================= attention: 8 waves, kv-split in block =======================
__global__ __launch_bounds__(512, 2) void attn_kernel(
    const short* __restrict__ Qb, const short* __restrict__ Kb,
    const short* __restrict__ Vt,
    const float* __restrict__ netW, const float* __restrict__ netb,
    float* __restrict__ out) {
  __shared__ char smem[98304];   // 2 groups x (K dbuf 32KB + V 16KB)

  const int bid = blockIdx.x;
  const int b = (bid & 7) * 2 + ((bid >> 3) & 1);   // batch <-> XCD affinity
  const int q0 = (bid >> 4) * 128;
  const int t = threadIdx.x;
  const int w = t >> 6, l = t & 63;
  const int gr = w >> 2, wq = w & 3;                // kv-group, q-subtile
  const int l31 = l & 31, h = l >> 5, l7 = l & 7;
  const int qw = q0 + wq * 32;
  const bool hb = (h != 0);

  const short* Kg = Kb + ((size_t)b * N_ + (size_t)gr * 1024) * DQ;
  const short* Vg = Vt + (size_t)b * DQ * N_;        // kv col offset += gr*1024
  char* kb0  = smem + gr * 49152;
  char* kb1  = kb0 + 16384;
  char* vbuf = kb0 + 32768;

  // Q fragments (32 q rows, full D=256)
  bf16x8 qf[16];
  const short* Qrow = Qb + ((size_t)b * N_ + qw + l31) * DQ + h * 8;
#pragma unroll
  for (int kc = 0; kc < 16; ++kc)
    qf[kc] = *(const bf16x8*)(Qrow + kc * 16);

  f32x16 o[8];
#pragma unroll
  for (int dt = 0; dt < 8; ++dt)
#pragma unroll
    for (int r = 0; r < 16; ++r) o[dt][r] = 0.f;
  float lsum = 0.f;

  // staging helpers (per-group; wq = wave index within group)
  auto stage_k = [&](int tile, char* dst) {
#pragma unroll
    for (int it = 0; it < 4; ++it) {
      int i = wq * 4 + it;
      int row = i * 2 + h;
      int gcol = (l31 * 16) ^ ((row & 7) << 4);
      const char* src = (const char*)(Kg + (size_t)(tile * KVB + row) * DQ) + gcol;
      __builtin_amdgcn_global_load_lds(
          (const __attribute__((address_space(1))) void*)src,
          (__attribute__((address_space(3))) void*)(dst + i * 1024), 16, 0, 0);
    }
  };
  bf16x8 vreg[4];
  auto load_v = [&](int tile) {
#pragma unroll
    for (int it = 0; it < 4; ++it) {
      int i = wq * 4 + it;
      int row = i * 16 + (l >> 2);
      int gcol = ((l & 3) * 16) ^ ((row & 3) << 4);
      vreg[it] = *(const bf16x8*)((const char*)(Vg + (size_t)row * N_) +
                                  gr * 2048 + tile * (KVB * 2) + gcol);
    }
  };
  auto write_v = [&]() {
#pragma unroll
    for (int it = 0; it < 4; ++it) {
      int i = wq * 4 + it;
      *(bf16x8*)(vbuf + i * 1024 + l * 16) = vreg[it];
    }
  };

  stage_k(0, kb0);
  load_v(0);
  __syncthreads();
  write_v();
  __syncthreads();

  const int vswz = (l31 & 3) << 4;
  for (int tt = 0; tt < 32; ++tt) {
    char* kc_ = (tt & 1) ? kb1 : kb0;
    if (tt < 31) {
      stage_k(tt + 1, (tt & 1) ? kb0 : kb1);
      load_v(tt + 1);
    }
    // QK^T (swapped: S^T[32 kv][32 q], q lane-local)
    f32x16 s;
#pragma unroll
    for (int r = 0; r < 16; ++r) s[r] = 0.f;
    __builtin_amdgcn_s_setprio(1);
#pragma unroll
    for (int kc = 0; kc < 16; ++kc) {
      bf16x8 kf = *(const bf16x8*)(kc_ + l31 * 512 + ((kc * 32 + h * 16) ^ (l7 << 4)));
      s = __builtin_amdgcn_mfma_f32_32x32x16_bf16(kf, qf[kc], s, 0, 0, 0);
    }
    __builtin_amdgcn_s_setprio(0);
    // softmax m=0 -> in-register P fragments
#pragma unroll
    for (int r = 0; r < 16; ++r) { s[r] = __expf(s[r]); lsum += s[r]; }
    unsigned wA = cvtpk(s[0], s[1]),   wB = cvtpk(s[2], s[3]);
    unsigned wC = cvtpk(s[4], s[5]),   wD = cvtpk(s[6], s[7]);
    unsigned wE = cvtpk(s[8], s[9]),   wF = cvtpk(s[10], s[11]);
    unsigned wG = cvtpk(s[12], s[13]), wH = cvtpk(s[14], s[15]);
    bf16x8 pf0 = mkfrag(wA, wB, wC, wD, hb);
    bf16x8 pf1 = mkfrag(wE, wF, wG, wH, hb);
    // PV: O^T[256 d][32 q]
    __builtin_amdgcn_s_setprio(1);
#pragma unroll
    for (int dt = 0; dt < 8; ++dt) {
      const char* vrow = vbuf + (dt * 32 + l31) * 64;
      bf16x8 v0 = *(const bf16x8*)(vrow + ((h * 16) ^ vswz));
      bf16x8 v1 = *(const bf16x8*)(vrow + ((32 + h * 16) ^ vswz));
      o[dt] = __builtin_amdgcn_mfma_f32_32x32x16_bf16(v0, pf0, o[dt], 0, 0, 0);
      o[dt] = __builtin_amdgcn_mfma_f32_32x32x16_bf16(v1, pf1, o[dt], 0, 0, 0);
    }
    __builtin_amdgcn_s_setprio(0);
    __syncthreads();            // drains K prefetch (vmcnt) + all waves done with vbuf
    if (tt < 31) write_v();
    __syncthreads();            // vbuf + next kbuf ready
  }

  lsum += __shfl_xor(lsum, 32);

  // ---- combine kv halves: wave w (gr=0) += wave w+4 (gr=1) ----
  float* lsums = (float*)(smem + 65536);
  if (w >= 4 && l < 32) lsums[(w - 4) * 32 + l] = lsum;

  auto write_o = [&](char* base) {
#pragma unroll
    for (int dt = 0; dt < 8; ++dt)
#pragma unroll
      for (int q = 0; q < 4; ++q) {
        f32x4 v;
        v[0] = o[dt][q * 4 + 0]; v[1] = o[dt][q * 4 + 1];
        v[2] = o[dt][q * 4 + 2]; v[3] = o[dt][q * 4 + 3];
        *(f32x4*)(base + ((dt * 4 + q) * 64 + l) * 16) = v;
      }
  };
  auto add_o = [&](const char* base) {
#pragma unroll
    for (int dt = 0; dt < 8; ++dt)
#pragma unroll
      for (int q = 0; q < 4; ++q) {
        f32x4 v = *(const f32x4*)(base + ((dt * 4 + q) * 64 + l) * 16);
        o[dt][q * 4 + 0] += v[0]; o[dt][q * 4 + 1] += v[1];
        o[dt][q * 4 + 2] += v[2]; o[dt][q * 4 + 3] += v[3];
      }
  };

  if (w == 4 || w == 5) write_o(smem + (w - 4) * 32768);
  __syncthreads();
  if (w == 0 || w == 1) add_o(smem + w * 32768);
  float ltot = (w < 4) ? (lsum + lsums[w * 32 + l31]) : 1.f;
  __syncthreads();
  if (w == 6 || w == 7) write_o(smem + (w - 6) * 32768);
  __syncthreads();
  if (w == 2 || w == 3) add_o(smem + (w - 2) * 32768);

  if (w < 4) {
    const float linv = 1.f / ltot;
    // O -> bf16 B-fragments
    bf16x8 of[16];
#pragma unroll
    for (int dt = 0; dt < 8; ++dt) {
      unsigned a0 = cvtpk(o[dt][0] * linv,  o[dt][1] * linv);
      unsigned a1 = cvtpk(o[dt][2] * linv,  o[dt][3] * linv);
      unsigned a2 = cvtpk(o[dt][4] * linv,  o[dt][5] * linv);
      unsigned a3 = cvtpk(o[dt][6] * linv,  o[dt][7] * linv);
      unsigned a4 = cvtpk(o[dt][8] * linv,  o[dt][9] * linv);
      unsigned a5 = cvtpk(o[dt][10] * linv, o[dt][11] * linv);
      unsigned a6 = cvtpk(o[dt][12] * linv, o[dt][13] * linv);
      unsigned a7 = cvtpk(o[dt][14] * linv, o[dt][15] * linv);
      of[dt * 2]     = mkfrag(a0, a1, a2, a3, hb);
      of[dt * 2 + 1] = mkfrag(a4, a5, a6, a7, hb);
    }
    // fused out-projection: out^T[128][q] = netW @ O
    float* orow = out + ((size_t)b * OUTR + qw + l31) * HID_;
#pragma unroll
    for (int ot = 0; ot < 4; ++ot) {
      f32x16 acc;
#pragma unroll
      for (int r = 0; r < 16; ++r) acc[r] = 0.f;
#pragma unroll
      for (int dc = 0; dc < 16; ++dc) {
        const float* wp = netW + (size_t)(ot * 32 + l31) * DQ + dc * 16 + h * 8;
        f32x4 w0 = *(const f32x4*)wp;
        f32x4 w1 = *(const f32x4*)(wp + 4);
        union { unsigned u[4]; bf16x8 v; } nf;
        nf.u[0] = cvtpk(w0[0], w0[1]); nf.u[1] = cvtpk(w0[2], w0[3]);
        nf.u[2] = cvtpk(w1[0], w1[1]); nf.u[3] = cvtpk(w1[2], w1[3]);
        acc = __builtin_amdgcn_mfma_f32_32x32x16_bf16(nf.v, of[dc], acc, 0, 0, 0);
      }
#pragma unroll
      for (int rq = 0; rq < 4; ++rq) {
        f32x4 bia = *(const f32x4*)(netb + ot * 32 + rq * 8 + h * 4);
        f32x4 vv;
        vv[0] = acc[4 * rq + 0] + bia[0];
        vv[1] = acc[4 * rq + 1] + bia[1];
        vv[2] = acc[4 * rq + 2] + bia[2];
        vv[3] = acc[4 * rq + 3] + bia[3];
        *(f32x4*)(orow + ot * 32 + rq * 8 + h * 4) = vv;
      }
    }
  }
}

extern "C" void kernel_launch(void* const* d_in, const int* in_sizes, int n_in,
                              void* d_out, int out_size, void* d_ws, size_t ws_size,
                              hipStream_t stream) {
  (void)in_sizes; (void)n_in; (void)out_size; (void)ws_size;
  const float* net_state  = (const float*)d_in[0];
  const float* sfc_state  = (const float*)d_in[1];
  const int*   node_pair  = (const int*)d_in[2];
  const float* Wq   = (const float*)d_in[3];
  const float* bq   = (const float*)d_in[4];
  const float* Wk   = (const float*)d_in[5];
  const float* bk   = (const float*)d_in[6];
  const float* Wv   = (const float*)d_in[7];
  const float* bv   = (const float*)d_in[8];
  const float* netW = (const float*)d_in[9];
  const float* netb = (const float*)d_in[10];
  const float* node_embed = (const float*)d_in[11];
  const float* sfcW = (const float*)d_in[12];
  const float* sfcb = (const float*)d_in[13];
  const float* pos  = (const float*)d_in[14];
  const float* qkvW = (const float*)d_in[15];
  const float* qkvB = (const float*)d_in[16];
  const float* outW = (const float*)d_in[17];
  const float* outB = (const float*)d_in[18];
  const float* ln1w = (const float*)d_in[19];
  const float* ln1b = (const float*)d_in[20];
  const float* l1w  = (const float*)d_in[21];
  const float* l1b  = (const float*)d_in[22];
  const float* l2w  = (const float*)d_in[23];
  const float* l2b  = (const float*)d_in[24];
  const float* ln2w = (const float*)d_in[25];
  const float* ln2b = (const float*)d_in[26];
  float* out = (float*)d_out;

  const size_t S = (size_t)B_ * N_ * DQ;
  short* Qb = (short*)d_ws;
  short* Kb = Qb + S;
  short* Vt = Kb + S;

  proj_sfc_kernel<<<272, 256, 0, stream>>>(net_state, Wq, bq, Wk, bk, Wv, bv, Qb, Kb, Vt,
                                           sfc_state, node_pair, node_embed, sfcW, sfcb, pos,
                                           qkvW, qkvB, outW, outB, ln1w, ln1b, l1w, l1b,
                                           l2w, l2b, ln2w, ln2b, out);
  attn_kernel<<<256, 512, 0, stream>>>(Qb, Kb, Vt, netW, netb, out);
}